// Round 8
// baseline (907.965 us; speedup 1.0000x reference)
//
#include <hip/hip_runtime.h>

// RoutingCapsule: x(16,2048,16) fp32, W(1,2048,64,32,16) fp32, bias(64,32) fp32
// -> v(16,64,32) fp32.   Routing collapses (b_logits additive from 0):
//   s0 = (1/64) sum_i u ; v0 = squash(s0+bias)
//   pass1: c1 = softmax_o(u.v0)      ; s1 = sum_i c1*u
//   pass2: c2 = softmax_o(u.(v0+v1)) ; out = squash(sum_i c2*u + bias)
//
// R14: R13 died on "container failed twice" (recurring source-independent
// infra mode; R8's identical resubmit ran fine in R9). Source re-audited:
// all indices in-bounds (parts max 8388607/8M, ws 64MB, LDS 141312B<160K,
// Wnext computed-but-never-deref'd at i=2047 tail). Resubmitting unchanged.
//
// R13 (stands): k_s0sweep rebuilt as a stripped clone of the PROVEN k_rsweep
// engine. R11/R12: register-prefetch s0sweep spilled twice (VGPR pinned 64,
// 0.7-1.1GB scratch traffic, 265/355us). The rsweep skeleton (512thr,
// bounds(512,2), global_load_lds W staging) compiled clean 3 rounds running
// -> reuse verbatim with routing stripped: acc[bb][d] += dot(xsv,W) only
// (~100 VGPR). part0 adopts part1's [b*256+g][od] layout so k_s0red is an
// exact copy of the proven k_s1red. Attribution (R10-R12): fills ~320us,
// rsweeps+reducers ~186us, R10-s0sweep ~124us. New s0sweep HBM-bound
// ~45-60us -> predict total ~550-580.
#define B_ 16
#define I_ 2048
#define OD_ 2048
#define EPSQ 1e-9f

typedef float v4f __attribute__((ext_vector_type(4)));

__device__ __forceinline__ float squashf(float s) {
  float sq = s * s;
  return sq / (1.0f + sq) * s * rsqrtf(sq + EPSQ);
}

__device__ __forceinline__ void gload16(const void* g, void* l) {
  __builtin_amdgcn_global_load_lds(
      (__attribute__((address_space(1))) const unsigned int*)g,
      (__attribute__((address_space(3))) unsigned int*)l, 16, 0, 0);
}

__device__ __forceinline__ float rfl(float v) {
  return __uint_as_float(__builtin_amdgcn_readfirstlane(__float_as_uint(v)));
}

// ---- shared staging macro (used by k_s0sweep and k_rsweep; both name their
// locals t/wv). Wave stages 8 o-slices (1 KB each) of a 64KB W d-half into a
// 65-float4-stride padded LDS buffer: linear per-instruction dest (required
// by global_load_lds), pad falls between instructions; stride 65 == 1 mod 8
// -> conflict-free ds_read_b128 on the consume side. ----
#define STAGE_HALF(row, half, buf)                                         \
  {                                                                        \
    _Pragma("unroll")                                                      \
    for (int k = 0; k < 8; ++k) {                                          \
      const int oo = wv + k * 8;                                           \
      const float* g = (row) + oo * 512 + (half) * 256 + (t & 63) * 4;     \
      gload16(g, (void*)((char*)(buf) + (size_t)(oo * 65) * 16));          \
    }                                                                      \
  }

// ---------------------------------------------------------------------------
// K1: s0 partials via the rsweep engine, routing stripped.
// 256 blocks x 512 thr (8 waves, 1 block/CU, LDS 141KB). Block owns 8 i.
// Wave wv owns b = 2wv, 2wv+1; lane = o. Per i: W row staged in two 64KB
// d-halves, double-buffered; x from 8KB LDS; acc[bb][d] += dot(x, Wslice).
// part0[(b*256 + blk)][od] : 32 MB (same layout as rsweep partials).
// ---------------------------------------------------------------------------
__global__ __launch_bounds__(512, 2) void k_s0sweep(
    const float* __restrict__ x, const float* __restrict__ W,
    float* __restrict__ part)
{
  __shared__ float4 bufA[64 * 65];     // 66560 B
  __shared__ float4 bufB[64 * 65];     // 66560 B
  __shared__ float  xls[8 * 16 * 16];  // [ii][b][p] 8 KB
  const int t = threadIdx.x;
  const int o = t & 63;
  const int wv = t >> 6;
  const int i0 = blockIdx.x * 8;

  // stage x[b, i0..i0+7, :] -> xls[ii][b][p]; identity-linear f4 mapping.
  {
    const int ii = t >> 6, b = (t >> 2) & 15, q = t & 3;
    ((float4*)xls)[ii * 64 + b * 4 + q] =
        ((const float4*)x)[(size_t)b * (I_ * 4) + (size_t)(i0 + ii) * 4 + q];
  }

  float accA[2][16], accB[2][16];
#pragma unroll
  for (int bb = 0; bb < 2; ++bb)
#pragma unroll
    for (int d = 0; d < 16; ++d) { accA[bb][d] = 0.f; accB[bb][d] = 0.f; }

  // prologue: A(0) staged+drained (sync also covers x staging); B(0) in flight
  const float* Wrow0 = W + (size_t)i0 * (OD_ * 16);
  STAGE_HALF(Wrow0, 0, bufA);
  __syncthreads();
  STAGE_HALF(Wrow0, 1, bufB);

  for (int ii = 0; ii < 8; ++ii) {
    const int i = i0 + ii;
    const float* Wnext = W + (size_t)(i + 1) * (OD_ * 16);

    // x from LDS (broadcast reads, wave-uniform) -> SGPRs
    float xsv[2][16];
#pragma unroll
    for (int bb = 0; bb < 2; ++bb) {
      const float* xp = xls + (size_t)ii * 256 + (wv * 2 + bb) * 16;
#pragma unroll
      for (int k = 0; k < 16; ++k) xsv[bb][k] = rfl(xp[k]);
    }

    // ---- accumulate half A (d = 0..15) from bufA ----
#pragma unroll
    for (int d = 0; d < 16; ++d) {
      const float4* wp = bufA + o * 65 + d * 4;
      float4 w0 = wp[0], w1 = wp[1], w2 = wp[2], w3 = wp[3];
#pragma unroll
      for (int bb = 0; bb < 2; ++bb) {
        float uu = xsv[bb][0] * w0.x;
        uu = fmaf(xsv[bb][1], w0.y, uu); uu = fmaf(xsv[bb][2], w0.z, uu);
        uu = fmaf(xsv[bb][3], w0.w, uu); uu = fmaf(xsv[bb][4], w1.x, uu);
        uu = fmaf(xsv[bb][5], w1.y, uu); uu = fmaf(xsv[bb][6], w1.z, uu);
        uu = fmaf(xsv[bb][7], w1.w, uu); uu = fmaf(xsv[bb][8], w2.x, uu);
        uu = fmaf(xsv[bb][9], w2.y, uu); uu = fmaf(xsv[bb][10], w2.z, uu);
        uu = fmaf(xsv[bb][11], w2.w, uu); uu = fmaf(xsv[bb][12], w3.x, uu);
        uu = fmaf(xsv[bb][13], w3.y, uu); uu = fmaf(xsv[bb][14], w3.z, uu);
        uu = fmaf(xsv[bb][15], w3.w, uu);
        accA[bb][d] += uu;
      }
    }
    __syncthreads();                 // bufB(ii) complete; all done with bufA
    if (ii < 7) STAGE_HALF(Wnext, 0, bufA);

    // ---- accumulate half B (d = 16..31) from bufB ----
#pragma unroll
    for (int d = 0; d < 16; ++d) {
      const float4* wp = bufB + o * 65 + d * 4;
      float4 w0 = wp[0], w1 = wp[1], w2 = wp[2], w3 = wp[3];
#pragma unroll
      for (int bb = 0; bb < 2; ++bb) {
        float uu = xsv[bb][0] * w0.x;
        uu = fmaf(xsv[bb][1], w0.y, uu); uu = fmaf(xsv[bb][2], w0.z, uu);
        uu = fmaf(xsv[bb][3], w0.w, uu); uu = fmaf(xsv[bb][4], w1.x, uu);
        uu = fmaf(xsv[bb][5], w1.y, uu); uu = fmaf(xsv[bb][6], w1.z, uu);
        uu = fmaf(xsv[bb][7], w1.w, uu); uu = fmaf(xsv[bb][8], w2.x, uu);
        uu = fmaf(xsv[bb][9], w2.y, uu); uu = fmaf(xsv[bb][10], w2.z, uu);
        uu = fmaf(xsv[bb][11], w2.w, uu); uu = fmaf(xsv[bb][12], w3.x, uu);
        uu = fmaf(xsv[bb][13], w3.y, uu); uu = fmaf(xsv[bb][14], w3.z, uu);
        uu = fmaf(xsv[bb][15], w3.w, uu);
        accB[bb][d] += uu;
      }
    }
    __syncthreads();                 // bufA(ii+1) complete; all done with bufB
    if (ii < 7) STAGE_HALF(Wnext, 1, bufB);
  }

  // ---- write per-(wave,b) partial: part[(b*256 + blk)][o*32 + d] ----
#pragma unroll
  for (int bb = 0; bb < 2; ++bb) {
    const int b = wv * 2 + bb;
    float4* dst = (float4*)(part + ((size_t)(b * 256 + blockIdx.x)) * OD_ + o * 32);
#pragma unroll
    for (int q = 0; q < 4; ++q) {
      float4 v0, v1;
      v0.x = accA[bb][q * 4 + 0]; v0.y = accA[bb][q * 4 + 1];
      v0.z = accA[bb][q * 4 + 2]; v0.w = accA[bb][q * 4 + 3];
      v1.x = accB[bb][q * 4 + 0]; v1.y = accB[bb][q * 4 + 1];
      v1.z = accB[bb][q * 4 + 2]; v1.w = accB[bb][q * 4 + 3];
      dst[q] = v0; dst[q + 4] = v1;
    }
  }
}

// ---------------------------------------------------------------------------
// K2: s0_raw[b,od] = sum_g part0[(b*256+g)][od].  grid=256 (16 b x 16 slices).
// (exact copy of the proven k_s1red structure)
// ---------------------------------------------------------------------------
__global__ __launch_bounds__(128) void k_s0red(
    const float* __restrict__ part0, float* __restrict__ s0)
{
  const int b = blockIdx.x >> 4;
  const int od = (blockIdx.x & 15) * 128 + threadIdx.x;
  float a = 0.f;
  const float* p = part0 + (size_t)b * 256 * OD_ + od;
#pragma unroll 8
  for (int g = 0; g < 256; ++g) a += p[(size_t)g * OD_];
  s0[b * OD_ + od] = a;
}

// ---------------------------------------------------------------------------
// K3: fused routing sweep — recomputes u from W/x, W streamed exactly once.
// 256 blocks x 512 thr (8 waves, 1 block/CU, LDS 141KB). Block owns 8 i.
// Wave wv owns b = 2wv, 2wv+1; lane = o. Per i: W row staged in two 64KB
// d-halves, double-buffered; x from 8KB LDS (staged once); u kept in regs;
// exact softmax per (b,i); one 8KB partial write per (wave,b).
// part[(b*256 + blk)][od] : 32 MB.
// ---------------------------------------------------------------------------
__global__ __launch_bounds__(512, 2) void k_rsweep(
    const float* __restrict__ x, const float* __restrict__ W,
    const float* __restrict__ sA, float scaleA,
    const float* __restrict__ sB,  // may be null
    const float* __restrict__ bias,
    float* __restrict__ part)
{
  __shared__ float4 bufA[64 * 65];   // 66560 B
  __shared__ float4 bufB[64 * 65];   // 66560 B
  __shared__ float  xls[8 * 16 * 16];  // [ii][b][p] 8 KB
  const int t = threadIdx.x;
  const int o = t & 63;
  const int wv = t >> 6;
  const int i0 = blockIdx.x * 8;

  // stage x[b, i0..i0+7, :] -> xls[ii][b][p]; identity-linear f4 mapping.
  {
    const int ii = t >> 6, b = (t >> 2) & 15, q = t & 3;
    ((float4*)xls)[ii * 64 + b * 4 + q] =
        ((const float4*)x)[(size_t)b * (I_ * 4) + (size_t)(i0 + ii) * 4 + q];
  }

  // vv = squash(sA*scaleA + bias) [+ squash(sB + bias)], per (bb, d)
  float vvA[2][16], vvB[2][16];
#pragma unroll
  for (int bb = 0; bb < 2; ++bb) {
    const int b = wv * 2 + bb;
    const float* sa = sA + b * OD_ + o * 32;
    const float* sb = sB ? sB + b * OD_ + o * 32 : nullptr;
    const float* bp = bias + o * 32;
#pragma unroll
    for (int d = 0; d < 16; ++d) {
      float bs0 = bp[d], bs1 = bp[d + 16];
      float va = squashf(sa[d] * scaleA + bs0);
      float vb = squashf(sa[d + 16] * scaleA + bs1);
      if (sb) { va += squashf(sb[d] + bs0); vb += squashf(sb[d + 16] + bs1); }
      vvA[bb][d] = va; vvB[bb][d] = vb;
    }
  }

  float accA[2][16], accB[2][16];
#pragma unroll
  for (int bb = 0; bb < 2; ++bb)
#pragma unroll
    for (int d = 0; d < 16; ++d) { accA[bb][d] = 0.f; accB[bb][d] = 0.f; }

  // prologue: A(0) staged+drained (sync also covers x staging); B(0) in flight
  const float* Wrow0 = W + (size_t)i0 * (OD_ * 16);
  STAGE_HALF(Wrow0, 0, bufA);
  __syncthreads();
  STAGE_HALF(Wrow0, 1, bufB);

  for (int ii = 0; ii < 8; ++ii) {
    const int i = i0 + ii;
    const float* Wnext = W + (size_t)(i + 1) * (OD_ * 16);

    // x from LDS (broadcast reads, wave-uniform) -> SGPRs
    float xsv[2][16];
#pragma unroll
    for (int bb = 0; bb < 2; ++bb) {
      const float* xp = xls + (size_t)ii * 256 + (wv * 2 + bb) * 16;
#pragma unroll
      for (int k = 0; k < 16; ++k) xsv[bb][k] = rfl(xp[k]);
    }

    float lg[2] = {0.f, 0.f};
    float uA[2][16], uB[2][16];

    // ---- compute half A (d = 0..15) from bufA ----
#pragma unroll
    for (int d = 0; d < 16; ++d) {
      const float4* wp = bufA + o * 65 + d * 4;
      float4 w0 = wp[0], w1 = wp[1], w2 = wp[2], w3 = wp[3];
#pragma unroll
      for (int bb = 0; bb < 2; ++bb) {
        float uu = xsv[bb][0] * w0.x;
        uu = fmaf(xsv[bb][1], w0.y, uu); uu = fmaf(xsv[bb][2], w0.z, uu);
        uu = fmaf(xsv[bb][3], w0.w, uu); uu = fmaf(xsv[bb][4], w1.x, uu);
        uu = fmaf(xsv[bb][5], w1.y, uu); uu = fmaf(xsv[bb][6], w1.z, uu);
        uu = fmaf(xsv[bb][7], w1.w, uu); uu = fmaf(xsv[bb][8], w2.x, uu);
        uu = fmaf(xsv[bb][9], w2.y, uu); uu = fmaf(xsv[bb][10], w2.z, uu);
        uu = fmaf(xsv[bb][11], w2.w, uu); uu = fmaf(xsv[bb][12], w3.x, uu);
        uu = fmaf(xsv[bb][13], w3.y, uu); uu = fmaf(xsv[bb][14], w3.z, uu);
        uu = fmaf(xsv[bb][15], w3.w, uu);
        uA[bb][d] = uu;
        lg[bb] = fmaf(uu, vvA[bb][d], lg[bb]);
      }
    }
    __syncthreads();                 // bufB(ii) complete; all done with bufA
    if (ii < 7) STAGE_HALF(Wnext, 0, bufA);

    // ---- compute half B (d = 16..31) from bufB ----
#pragma unroll
    for (int d = 0; d < 16; ++d) {
      const float4* wp = bufB + o * 65 + d * 4;
      float4 w0 = wp[0], w1 = wp[1], w2 = wp[2], w3 = wp[3];
#pragma unroll
      for (int bb = 0; bb < 2; ++bb) {
        float uu = xsv[bb][0] * w0.x;
        uu = fmaf(xsv[bb][1], w0.y, uu); uu = fmaf(xsv[bb][2], w0.z, uu);
        uu = fmaf(xsv[bb][3], w0.w, uu); uu = fmaf(xsv[bb][4], w1.x, uu);
        uu = fmaf(xsv[bb][5], w1.y, uu); uu = fmaf(xsv[bb][6], w1.z, uu);
        uu = fmaf(xsv[bb][7], w1.w, uu); uu = fmaf(xsv[bb][8], w2.x, uu);
        uu = fmaf(xsv[bb][9], w2.y, uu); uu = fmaf(xsv[bb][10], w2.z, uu);
        uu = fmaf(xsv[bb][11], w2.w, uu); uu = fmaf(xsv[bb][12], w3.x, uu);
        uu = fmaf(xsv[bb][13], w3.y, uu); uu = fmaf(xsv[bb][14], w3.z, uu);
        uu = fmaf(xsv[bb][15], w3.w, uu);
        uB[bb][d] = uu;
        lg[bb] = fmaf(uu, vvB[bb][d], lg[bb]);
      }
    }

    // ---- exact softmax over o (64 lanes) per bb, then accumulate ----
#pragma unroll
    for (int bb = 0; bb < 2; ++bb) {
      float m = lg[bb];
#pragma unroll
      for (int off = 32; off > 0; off >>= 1) m = fmaxf(m, __shfl_xor(m, off, 64));
      float ex = __expf(lg[bb] - m);
      float sm = ex;
#pragma unroll
      for (int off = 32; off > 0; off >>= 1) sm += __shfl_xor(sm, off, 64);
      float c = ex * __builtin_amdgcn_rcpf(sm);
#pragma unroll
      for (int d = 0; d < 16; ++d) {
        accA[bb][d] = fmaf(c, uA[bb][d], accA[bb][d]);
        accB[bb][d] = fmaf(c, uB[bb][d], accB[bb][d]);
      }
    }
    __syncthreads();                 // bufA(ii+1) complete; all done with bufB
    if (ii < 7) STAGE_HALF(Wnext, 1, bufB);
  }

  // ---- write per-(wave,b) partial: part[(b*256 + blk)][o*32 + d] ----
#pragma unroll
  for (int bb = 0; bb < 2; ++bb) {
    const int b = wv * 2 + bb;
    float4* dst = (float4*)(part + ((size_t)(b * 256 + blockIdx.x)) * OD_ + o * 32);
#pragma unroll
    for (int q = 0; q < 4; ++q) {
      float4 v0, v1;
      v0.x = accA[bb][q * 4 + 0]; v0.y = accA[bb][q * 4 + 1];
      v0.z = accA[bb][q * 4 + 2]; v0.w = accA[bb][q * 4 + 3];
      v1.x = accB[bb][q * 4 + 0]; v1.y = accB[bb][q * 4 + 1];
      v1.z = accB[bb][q * 4 + 2]; v1.w = accB[bb][q * 4 + 3];
      dst[q] = v0; dst[q + 4] = v1;
    }
  }
}

// ---------------------------------------------------------------------------
// K4: s1[b,od] = sum_g part[(b*256+g)][od].  grid=256 (16 b x 16 slices).
// ---------------------------------------------------------------------------
__global__ __launch_bounds__(128) void k_s1red(
    const float* __restrict__ part, float* __restrict__ s1)
{
  const int b = blockIdx.x >> 4;
  const int od = (blockIdx.x & 15) * 128 + threadIdx.x;
  float a = 0.f;
  const float* p = part + (size_t)b * 256 * OD_ + od;
#pragma unroll 8
  for (int g = 0; g < 256; ++g) a += p[(size_t)g * OD_];
  s1[b * OD_ + od] = a;
}

// ---------------------------------------------------------------------------
// K5: out[b,od] = squash(sum_g part2 + bias).  grid=256.
// ---------------------------------------------------------------------------
__global__ __launch_bounds__(128) void k_outred(
    const float* __restrict__ part, const float* __restrict__ bias,
    float* __restrict__ out)
{
  const int b = blockIdx.x >> 4;
  const int od = (blockIdx.x & 15) * 128 + threadIdx.x;
  float a = 0.f;
  const float* p = part + (size_t)b * 256 * OD_ + od;
#pragma unroll 8
  for (int g = 0; g < 256; ++g) a += p[(size_t)g * OD_];
  out[b * OD_ + od] = squashf(a + bias[od]);
}

extern "C" void kernel_launch(void* const* d_in, const int* in_sizes, int n_in,
                              void* d_out, int out_size, void* d_ws, size_t ws_size,
                              hipStream_t stream) {
  const float* x = (const float*)d_in[0];
  const float* W = (const float*)d_in[1];
  const float* bias = (const float*)d_in[2];
  float* out = (float*)d_out;

  char* ws = (char*)d_ws;
  float* part0 = (float*)ws;                          // 32 MB s0 partials
  float* part1 = (float*)(ws + 33554432ull);          // 32 MB route partials
  float* part2 = part0;                               // reuse: part0 dead after K2
  float* s0    = (float*)(ws + 67108864ull);          // 128 KB
  float* s1    = s0 + 32768;                          // 128 KB

  k_s0sweep<<<dim3(256),  dim3(512), 0, stream>>>(x, W, part0);
  k_s0red  <<<dim3(256),  dim3(128), 0, stream>>>(part0, s0);
  // pass1: v0 = squash(s0/64 + bias)
  k_rsweep <<<dim3(256),  dim3(512), 0, stream>>>(x, W, s0, 1.0f / 64.0f, nullptr, bias, part1);
  k_s1red  <<<dim3(256),  dim3(128), 0, stream>>>(part1, s1);
  // pass2: vv = squash(s0/64+bias) + squash(s1+bias)
  k_rsweep <<<dim3(256),  dim3(512), 0, stream>>>(x, W, s0, 1.0f / 64.0f, s1, bias, part2);
  k_outred <<<dim3(256),  dim3(128), 0, stream>>>(part2, bias, out);
}

// Round 9
// 622.543 us; speedup vs baseline: 1.4585x; 1.4585x over previous
//
#include <hip/hip_runtime.h>

// RoutingCapsule: x(16,2048,16) fp32, W(1,2048,64,32,16) fp32, bias(64,32) fp32
// -> v(16,64,32) fp32.   Routing collapses (b_logits additive from 0):
//   s0 = (1/64) sum_i u ; v0 = squash(s0+bias)
//   pass1: c1 = softmax_o(u.v0)      ; s1 = sum_i c1*u
//   pass2: c2 = softmax_o(u.(v0+v1)) ; out = squash(sum_i c2*u + bias)
//
// R15: REVERT to R10-exact (best measured: 630us) + one micro-change.
// R11-R14 post-mortem: three s0sweep restructures all spilled (allocator
// repeatedly chose VGPR 32/64/128 < need and emitted 0.7-1.1GB scratch
// traffic; R14's "stripped LDS engine" FETCH 578/WRITE 808 vs ideal 258/32).
// Cross-round attribution is stable: total = ~506us (fills ~320 + rsweeps
// ~160 + reducers ~25) + s0sweep. Only the R9/R10 wc/wn double-buffered
// s0sweep never spilled (VGPR 40, clean counters) at ~124us. Reverting to it
// and to R10's rsweep/reducers/launcher verbatim.
// Single change: W loads in s0sweep are now PLAIN (no nontemporal) — W is
// 256MB = LLC-sized and rsweep pass 1 re-reads it ~10us later (only s0red's
// 64MB intervenes); cached W gives pass 1 a shot at LLC hits. nt gave zero
// benefit and forbids reuse.
#define B_ 16
#define I_ 2048
#define OD_ 2048
#define EPSQ 1e-9f

typedef float v4f __attribute__((ext_vector_type(4)));

__device__ __forceinline__ float squashf(float s) {
  float sq = s * s;
  return sq / (1.0f + sq) * s * rsqrtf(sq + EPSQ);
}

__device__ __forceinline__ float dot4(v4f a, v4f b) {
  return a.x * b.x + a.y * b.y + a.z * b.z + a.w * b.w;
}

__device__ __forceinline__ void gload16(const void* g, void* l) {
  __builtin_amdgcn_global_load_lds(
      (__attribute__((address_space(1))) const unsigned int*)g,
      (__attribute__((address_space(3))) unsigned int*)l, 16, 0, 0);
}

__device__ __forceinline__ float rfl(float v) {
  return __uint_as_float(__builtin_amdgcn_readfirstlane(__float_as_uint(v)));
}

// ---- staging macro for k_rsweep (locals t/wv in scope at expansion).
// Wave stages 8 o-slices (1 KB each) of a 64KB W d-half into a
// 65-float4-stride padded LDS buffer: linear per-instruction dest (required
// by global_load_lds), pad falls between instructions; stride 65 == 1 mod 8
// -> conflict-free ds_read_b128 on the consume side. ----
#define STAGE_HALF(row, half, buf)                                         \
  {                                                                        \
    _Pragma("unroll")                                                      \
    for (int k = 0; k < 8; ++k) {                                          \
      const int oo = wv + k * 8;                                           \
      const float* g = (row) + oo * 512 + (half) * 256 + (t & 63) * 4;     \
      gload16(g, (void*)((char*)(buf) + (size_t)(oo * 65) * 16));          \
    }                                                                      \
  }

// ---------------------------------------------------------------------------
// K1: s0 partials only (no u materialization).  [R10-exact, nt dropped]
// grid=2048: bx&7 = od-eighth e, bx>>3 = i-chunk ic (8 i each). Thread owns
// od = e*256+t. x staged in LDS (8KB); W register double-buffered (wc/wn).
// part0[ic][b][od] : 256*16*2048 fp32 = 32 MB.
// ---------------------------------------------------------------------------
__global__ __launch_bounds__(256, 4) void k_s0sweep(
    const float* __restrict__ x, const float* __restrict__ W,
    float* __restrict__ part0)
{
  __shared__ float xs[8 * 16 * 16];  // [ii][b][p] 8 KB
  const int t = threadIdx.x;
  const int e = blockIdx.x & 7;
  const int ic = blockIdx.x >> 3;
  const int i0 = ic * 8;
  const int od = e * 256 + t;

  {
    const int b = t >> 4, j = t & 15;
    const float4* src = (const float4*)(x + (size_t)(b * I_ + i0) * 16);
    float4 a0 = src[j * 2], a1 = src[j * 2 + 1];
    const int ii = j >> 1, pq = (j & 1) * 2;
    float4* dst = (float4*)xs + ii * 64 + b * 4;
    dst[pq] = a0; dst[pq + 1] = a1;
  }
  __syncthreads();

  float s0acc[B_];
#pragma unroll
  for (int b = 0; b < B_; ++b) s0acc[b] = 0.f;

  const v4f* wb = (const v4f*)(W + ((size_t)i0 * OD_ + od) * 16);
  v4f wc[4], wn[4];
#pragma unroll
  for (int k = 0; k < 4; ++k) wc[k] = wb[k];

  for (int ii = 0; ii < 8; ++ii) {
    if (ii < 7) {
      const v4f* wnp = wb + (size_t)(ii + 1) * 8192;
#pragma unroll
      for (int k = 0; k < 4; ++k) wn[k] = wnp[k];
    }
    const v4f* xv = (const v4f*)xs + ii * 64;
#pragma unroll
    for (int b = 0; b < B_; ++b) {
      v4f x0 = xv[b * 4 + 0], x1 = xv[b * 4 + 1];
      v4f x2 = xv[b * 4 + 2], x3 = xv[b * 4 + 3];
      s0acc[b] += dot4(x0, wc[0]) + dot4(x1, wc[1]) +
                  dot4(x2, wc[2]) + dot4(x3, wc[3]);
    }
    if (ii < 7) {
#pragma unroll
      for (int k = 0; k < 4; ++k) wc[k] = wn[k];
    }
  }
#pragma unroll
  for (int b = 0; b < B_; ++b)
    part0[((size_t)ic * B_ + b) * OD_ + od] = s0acc[b];
}

// ---------------------------------------------------------------------------
// K2: s0_raw[b,od] = sum_ic part0[ic][b][od].  grid=128: b=bx>>3, od block.
// ---------------------------------------------------------------------------
__global__ __launch_bounds__(256) void k_s0red(
    const float* __restrict__ part0, float* __restrict__ s0)
{
  const int b = blockIdx.x >> 3;
  const int od = (blockIdx.x & 7) * 256 + threadIdx.x;
  float a = 0.f;
  const float* p = part0 + (size_t)b * OD_ + od;
#pragma unroll 8
  for (int ic = 0; ic < 256; ++ic) a += p[(size_t)ic * B_ * OD_];
  s0[b * OD_ + od] = a;
}

// ---------------------------------------------------------------------------
// K3: fused routing sweep — recomputes u from W/x, W streamed exactly once.
// [R10-exact] 256 blocks x 512 thr (8 waves, 1 block/CU, LDS 133KB). Block
// owns 8 i. Wave wv owns b = 2wv, 2wv+1; lane = o. Per i: W row staged in two
// 64KB d-halves, double-buffered; u kept in regs; exact softmax per (b,i);
// one 8KB partial write per (wave,b).  part[(b*256 + blk)][od] : 32 MB.
// ---------------------------------------------------------------------------
__global__ __launch_bounds__(512, 2) void k_rsweep(
    const float* __restrict__ x, const float* __restrict__ W,
    const float* __restrict__ sA, float scaleA,
    const float* __restrict__ sB,  // may be null
    const float* __restrict__ bias,
    float* __restrict__ part)
{
  __shared__ float4 bufA[64 * 65];   // 66560 B
  __shared__ float4 bufB[64 * 65];   // 66560 B
  const int t = threadIdx.x;
  const int o = t & 63;
  const int wv = t >> 6;
  const int i0 = blockIdx.x * 8;

  // vv = squash(sA*scaleA + bias) [+ squash(sB + bias)], per (bb, d)
  float vvA[2][16], vvB[2][16];
#pragma unroll
  for (int bb = 0; bb < 2; ++bb) {
    const int b = wv * 2 + bb;
    const float* sa = sA + b * OD_ + o * 32;
    const float* sb = sB ? sB + b * OD_ + o * 32 : nullptr;
    const float* bp = bias + o * 32;
#pragma unroll
    for (int d = 0; d < 16; ++d) {
      float bs0 = bp[d], bs1 = bp[d + 16];
      float va = squashf(sa[d] * scaleA + bs0);
      float vb = squashf(sa[d + 16] * scaleA + bs1);
      if (sb) { va += squashf(sb[d] + bs0); vb += squashf(sb[d + 16] + bs1); }
      vvA[bb][d] = va; vvB[bb][d] = vb;
    }
  }

  float accA[2][16], accB[2][16];
#pragma unroll
  for (int bb = 0; bb < 2; ++bb)
#pragma unroll
    for (int d = 0; d < 16; ++d) { accA[bb][d] = 0.f; accB[bb][d] = 0.f; }

  // prologue: A(0) staged+drained; B(0) in flight
  const float* Wrow0 = W + (size_t)i0 * (OD_ * 16);
  STAGE_HALF(Wrow0, 0, bufA);
  __syncthreads();
  STAGE_HALF(Wrow0, 1, bufB);

  for (int ii = 0; ii < 8; ++ii) {
    const int i = i0 + ii;
    const float* Wnext = W + (size_t)(i + 1) * (OD_ * 16);

    // x -> SGPRs (uniform per wave-iteration)
    float xsv[2][16];
#pragma unroll
    for (int bb = 0; bb < 2; ++bb) {
      const float4* xp = (const float4*)(x + ((size_t)((wv * 2 + bb) * I_) + i) * 16);
#pragma unroll
      for (int q = 0; q < 4; ++q) {
        float4 xq = xp[q];
        xsv[bb][q * 4 + 0] = rfl(xq.x); xsv[bb][q * 4 + 1] = rfl(xq.y);
        xsv[bb][q * 4 + 2] = rfl(xq.z); xsv[bb][q * 4 + 3] = rfl(xq.w);
      }
    }

    float lg[2] = {0.f, 0.f};
    float uA[2][16], uB[2][16];

    // ---- compute half A (d = 0..15) from bufA ----
#pragma unroll
    for (int d = 0; d < 16; ++d) {
      const float4* wp = bufA + o * 65 + d * 4;
      float4 w0 = wp[0], w1 = wp[1], w2 = wp[2], w3 = wp[3];
#pragma unroll
      for (int bb = 0; bb < 2; ++bb) {
        float uu = xsv[bb][0] * w0.x;
        uu = fmaf(xsv[bb][1], w0.y, uu); uu = fmaf(xsv[bb][2], w0.z, uu);
        uu = fmaf(xsv[bb][3], w0.w, uu); uu = fmaf(xsv[bb][4], w1.x, uu);
        uu = fmaf(xsv[bb][5], w1.y, uu); uu = fmaf(xsv[bb][6], w1.z, uu);
        uu = fmaf(xsv[bb][7], w1.w, uu); uu = fmaf(xsv[bb][8], w2.x, uu);
        uu = fmaf(xsv[bb][9], w2.y, uu); uu = fmaf(xsv[bb][10], w2.z, uu);
        uu = fmaf(xsv[bb][11], w2.w, uu); uu = fmaf(xsv[bb][12], w3.x, uu);
        uu = fmaf(xsv[bb][13], w3.y, uu); uu = fmaf(xsv[bb][14], w3.z, uu);
        uu = fmaf(xsv[bb][15], w3.w, uu);
        uA[bb][d] = uu;
        lg[bb] = fmaf(uu, vvA[bb][d], lg[bb]);
      }
    }
    __syncthreads();                 // bufB(ii) complete; all done with bufA
    if (ii < 7) STAGE_HALF(Wnext, 0, bufA);

    // ---- compute half B (d = 16..31) from bufB ----
#pragma unroll
    for (int d = 0; d < 16; ++d) {
      const float4* wp = bufB + o * 65 + d * 4;
      float4 w0 = wp[0], w1 = wp[1], w2 = wp[2], w3 = wp[3];
#pragma unroll
      for (int bb = 0; bb < 2; ++bb) {
        float uu = xsv[bb][0] * w0.x;
        uu = fmaf(xsv[bb][1], w0.y, uu); uu = fmaf(xsv[bb][2], w0.z, uu);
        uu = fmaf(xsv[bb][3], w0.w, uu); uu = fmaf(xsv[bb][4], w1.x, uu);
        uu = fmaf(xsv[bb][5], w1.y, uu); uu = fmaf(xsv[bb][6], w1.z, uu);
        uu = fmaf(xsv[bb][7], w1.w, uu); uu = fmaf(xsv[bb][8], w2.x, uu);
        uu = fmaf(xsv[bb][9], w2.y, uu); uu = fmaf(xsv[bb][10], w2.z, uu);
        uu = fmaf(xsv[bb][11], w2.w, uu); uu = fmaf(xsv[bb][12], w3.x, uu);
        uu = fmaf(xsv[bb][13], w3.y, uu); uu = fmaf(xsv[bb][14], w3.z, uu);
        uu = fmaf(xsv[bb][15], w3.w, uu);
        uB[bb][d] = uu;
        lg[bb] = fmaf(uu, vvB[bb][d], lg[bb]);
      }
    }

    // ---- exact softmax over o (64 lanes) per bb, then accumulate ----
#pragma unroll
    for (int bb = 0; bb < 2; ++bb) {
      float m = lg[bb];
#pragma unroll
      for (int off = 32; off > 0; off >>= 1) m = fmaxf(m, __shfl_xor(m, off, 64));
      float ex = __expf(lg[bb] - m);
      float sm = ex;
#pragma unroll
      for (int off = 32; off > 0; off >>= 1) sm += __shfl_xor(sm, off, 64);
      float c = ex * __builtin_amdgcn_rcpf(sm);
#pragma unroll
      for (int d = 0; d < 16; ++d) {
        accA[bb][d] = fmaf(c, uA[bb][d], accA[bb][d]);
        accB[bb][d] = fmaf(c, uB[bb][d], accB[bb][d]);
      }
    }
    __syncthreads();                 // bufA(ii+1) complete; all done with bufB
    if (ii < 7) STAGE_HALF(Wnext, 1, bufB);
  }

  // ---- write per-(wave,b) partial: part[(b*256 + blk)][o*32 + d] ----
#pragma unroll
  for (int bb = 0; bb < 2; ++bb) {
    const int b = wv * 2 + bb;
    float4* dst = (float4*)(part + ((size_t)(b * 256 + blockIdx.x)) * OD_ + o * 32);
#pragma unroll
    for (int q = 0; q < 4; ++q) {
      float4 v0, v1;
      v0.x = accA[bb][q * 4 + 0]; v0.y = accA[bb][q * 4 + 1];
      v0.z = accA[bb][q * 4 + 2]; v0.w = accA[bb][q * 4 + 3];
      v1.x = accB[bb][q * 4 + 0]; v1.y = accB[bb][q * 4 + 1];
      v1.z = accB[bb][q * 4 + 2]; v1.w = accB[bb][q * 4 + 3];
      dst[q] = v0; dst[q + 4] = v1;
    }
  }
}

// ---------------------------------------------------------------------------
// K4: s1[b,od] = sum_g part[(b*256+g)][od].  grid=128.
// ---------------------------------------------------------------------------
__global__ __launch_bounds__(256) void k_s1red(
    const float* __restrict__ part, float* __restrict__ s1)
{
  const int b = blockIdx.x >> 3;
  const int od = (blockIdx.x & 7) * 256 + threadIdx.x;
  float a = 0.f;
  const float* p = part + (size_t)b * 256 * OD_ + od;
#pragma unroll 8
  for (int g = 0; g < 256; ++g) a += p[(size_t)g * OD_];
  s1[b * OD_ + od] = a;
}

// ---------------------------------------------------------------------------
// K5: out[b,od] = squash(sum_g part2 + bias).  grid=128.
// ---------------------------------------------------------------------------
__global__ __launch_bounds__(256) void k_outred(
    const float* __restrict__ part, const float* __restrict__ bias,
    float* __restrict__ out)
{
  const int b = blockIdx.x >> 3;
  const int od = (blockIdx.x & 7) * 256 + threadIdx.x;
  float a = 0.f;
  const float* p = part + (size_t)b * 256 * OD_ + od;
#pragma unroll 8
  for (int g = 0; g < 256; ++g) a += p[(size_t)g * OD_];
  out[b * OD_ + od] = squashf(a + bias[od]);
}

extern "C" void kernel_launch(void* const* d_in, const int* in_sizes, int n_in,
                              void* d_out, int out_size, void* d_ws, size_t ws_size,
                              hipStream_t stream) {
  const float* x = (const float*)d_in[0];
  const float* W = (const float*)d_in[1];
  const float* bias = (const float*)d_in[2];
  float* out = (float*)d_out;

  char* ws = (char*)d_ws;
  float* part0 = (float*)ws;                          // 32 MB s0 partials
  float* part1 = (float*)(ws + 33554432ull);          // 32 MB route partials
  float* part2 = part0;                               // reuse: part0 dead after K2
  float* s0    = (float*)(ws + 67108864ull);          // 128 KB
  float* s1    = s0 + 32768;                          // 128 KB

  k_s0sweep<<<dim3(2048), dim3(256), 0, stream>>>(x, W, part0);
  k_s0red  <<<dim3(128),  dim3(256), 0, stream>>>(part0, s0);
  // pass1: v0 = squash(s0/64 + bias)
  k_rsweep <<<dim3(256),  dim3(512), 0, stream>>>(x, W, s0, 1.0f / 64.0f, nullptr, bias, part1);
  k_s1red  <<<dim3(128),  dim3(256), 0, stream>>>(part1, s1);
  // pass2: vv = squash(s0/64+bias) + squash(s1+bias)
  k_rsweep <<<dim3(256),  dim3(512), 0, stream>>>(x, W, s0, 1.0f / 64.0f, s1, bias, part2);
  k_outred <<<dim3(128),  dim3(256), 0, stream>>>(part2, bias, out);
}

// Round 10
// 622.292 us; speedup vs baseline: 1.4591x; 1.0004x over previous
//
#include <hip/hip_runtime.h>

// RoutingCapsule: x(16,2048,16) fp32, W(1,2048,64,32,16) fp32, bias(64,32) fp32
// -> v(16,64,32) fp32.   Routing collapses (b_logits additive from 0):
//   s0 = (1/64) sum_i u ; v0 = squash(s0+bias)
//   pass1: c1 = softmax_o(u.v0)      ; s1 = sum_i c1*u
//   pass2: c2 = softmax_o(u.(v0+v1)) ; out = squash(sum_i c2*u + bias)
//
// R16: coalesce k_s0sweep's W stream via SMALL-SCALE gload_lds staging.
// R15 = 622.5us (session best). Budget: ~320us poison fills + ~302us ours
// (floor 153). s0sweep = ~124us at 2.3TB/s: its W loads are 64B-lane-strided
// (thread owns 1 od -> 4x16B at t*64) = per-inst gather over 32+ cache lines,
// plus wc/wn prefetch forces vmcnt(0) each ii with only 64B/thread in flight.
// Fix (minimal delta; R11/R12/R14 taught: don't grow registers): keep R15
// s0sweep grid/bounds/decomp/x-LDS/acc/write EXACTLY; swap the register W
// double-buffer for two 16KB LDS buffers staged by 4 gload16/thread/ii —
// 64 lanes x 16B CONTIGUOUS per inst (the rsweep-verified pattern), LDS dest
// wave-uniform + lane*16, linear (no padding; both-sides-or-neither rule).
// Consume: 4x ds_read_b128 per thread (4-way bank alias ~2Kcyc/CU/ii, hidden
// under 6.5Kcyc memory). VGPR ~70, LDS 40960B = exactly 4 blocks/CU.
// rsweep/reducers/launcher: byte-identical to R15.
#define B_ 16
#define I_ 2048
#define OD_ 2048
#define EPSQ 1e-9f

typedef float v4f __attribute__((ext_vector_type(4)));

__device__ __forceinline__ float squashf(float s) {
  float sq = s * s;
  return sq / (1.0f + sq) * s * rsqrtf(sq + EPSQ);
}

__device__ __forceinline__ float dot4(v4f a, v4f b) {
  return a.x * b.x + a.y * b.y + a.z * b.z + a.w * b.w;
}

__device__ __forceinline__ void gload16(const void* g, void* l) {
  __builtin_amdgcn_global_load_lds(
      (__attribute__((address_space(1))) const unsigned int*)g,
      (__attribute__((address_space(3))) unsigned int*)l, 16, 0, 0);
}

__device__ __forceinline__ float rfl(float v) {
  return __uint_as_float(__builtin_amdgcn_readfirstlane(__float_as_uint(v)));
}

// ---- staging macro for k_rsweep (locals t/wv in scope at expansion).
// Wave stages 8 o-slices (1 KB each) of a 64KB W d-half into a
// 65-float4-stride padded LDS buffer: linear per-instruction dest (required
// by global_load_lds), pad falls between instructions; stride 65 == 1 mod 8
// -> conflict-free ds_read_b128 on the consume side. ----
#define STAGE_HALF(row, half, buf)                                         \
  {                                                                        \
    _Pragma("unroll")                                                      \
    for (int k = 0; k < 8; ++k) {                                          \
      const int oo = wv + k * 8;                                           \
      const float* g = (row) + oo * 512 + (half) * 256 + (t & 63) * 4;     \
      gload16(g, (void*)((char*)(buf) + (size_t)(oo * 65) * 16));          \
    }                                                                      \
  }

// ---------------------------------------------------------------------------
// K1: s0 partials only (no u materialization).
// grid=2048: bx&7 = od-eighth e, bx>>3 = i-chunk ic (8 i each). Thread owns
// od = e*256+t. x staged in LDS (8KB). W slice (16KB/ii, the CONTIGUOUS bytes
// [e*16KB,(e+1)*16KB) of row i) staged into LDS double-buffer via gload16:
// chunk = wv + k*4 (16 x 1KB), dest = buf + chunk*1024 (+lane*16 by HW),
// src = slice + chunk*256 + lane*4 floats -> fully coalesced.
// part0[ic][b][od] : 256*16*2048 fp32 = 32 MB.
// ---------------------------------------------------------------------------
__global__ __launch_bounds__(256, 4) void k_s0sweep(
    const float* __restrict__ x, const float* __restrict__ W,
    float* __restrict__ part0)
{
  __shared__ v4f  wbuf[2][1024];     // 2 x 16 KB
  __shared__ float xs[8 * 16 * 16];  // [ii][b][p] 8 KB
  const int t = threadIdx.x;
  const int wv = t >> 6;
  const int e = blockIdx.x & 7;
  const int ic = blockIdx.x >> 3;
  const int i0 = ic * 8;
  const int od = e * 256 + t;

  // stage x[b, i0..i0+7, :] -> xs[ii][b][p]  (R15-exact)
  {
    const int b = t >> 4, j = t & 15;
    const float4* src = (const float4*)(x + (size_t)(b * I_ + i0) * 16);
    float4 a0 = src[j * 2], a1 = src[j * 2 + 1];
    const int ii = j >> 1, pq = (j & 1) * 2;
    float4* dst = (float4*)xs + ii * 64 + b * 4;
    dst[pq] = a0; dst[pq + 1] = a1;
  }

#define S0_STAGE(iidx, bufidx)                                             \
  {                                                                        \
    const float* sb_ = W + ((size_t)(i0 + (iidx)) * OD_ + e * 256) * 16;   \
    _Pragma("unroll")                                                      \
    for (int k = 0; k < 4; ++k) {                                          \
      const int ch = wv + k * 4;                                           \
      gload16(sb_ + ch * 256 + (t & 63) * 4,                               \
              (void*)((char*)(&wbuf[bufidx][0]) + ch * 1024));             \
    }                                                                      \
  }

  float s0acc[B_];
#pragma unroll
  for (int b = 0; b < B_; ++b) s0acc[b] = 0.f;

  S0_STAGE(0, 0);
  __syncthreads();   // x staging + buf0 (vmcnt drained by barrier)

  for (int ii = 0; ii < 8; ++ii) {
    if (ii < 7) S0_STAGE(ii + 1, (ii + 1) & 1);  // async, lands by next barrier

    const v4f* wp = &wbuf[ii & 1][t * 4];
    v4f w0 = wp[0], w1 = wp[1], w2 = wp[2], w3 = wp[3];
    const v4f* xv = (const v4f*)xs + ii * 64;
#pragma unroll
    for (int b = 0; b < B_; ++b) {
      v4f x0 = xv[b * 4 + 0], x1 = xv[b * 4 + 1];
      v4f x2 = xv[b * 4 + 2], x3 = xv[b * 4 + 3];
      s0acc[b] += dot4(x0, w0) + dot4(x1, w1) +
                  dot4(x2, w2) + dot4(x3, w3);
    }
    __syncthreads();  // readers done with buf[ii&1]; stage(ii+1) complete
  }
#undef S0_STAGE

#pragma unroll
  for (int b = 0; b < B_; ++b)
    part0[((size_t)ic * B_ + b) * OD_ + od] = s0acc[b];
}

// ---------------------------------------------------------------------------
// K2: s0_raw[b,od] = sum_ic part0[ic][b][od].  grid=128: b=bx>>3, od block.
// ---------------------------------------------------------------------------
__global__ __launch_bounds__(256) void k_s0red(
    const float* __restrict__ part0, float* __restrict__ s0)
{
  const int b = blockIdx.x >> 3;
  const int od = (blockIdx.x & 7) * 256 + threadIdx.x;
  float a = 0.f;
  const float* p = part0 + (size_t)b * OD_ + od;
#pragma unroll 8
  for (int ic = 0; ic < 256; ++ic) a += p[(size_t)ic * B_ * OD_];
  s0[b * OD_ + od] = a;
}

// ---------------------------------------------------------------------------
// K3: fused routing sweep — recomputes u from W/x, W streamed exactly once.
// [R15-exact] 256 blocks x 512 thr (8 waves, 1 block/CU, LDS 133KB). Block
// owns 8 i. Wave wv owns b = 2wv, 2wv+1; lane = o. Per i: W row staged in two
// 64KB d-halves, double-buffered; u kept in regs; exact softmax per (b,i);
// one 8KB partial write per (wave,b).  part[(b*256 + blk)][od] : 32 MB.
// ---------------------------------------------------------------------------
__global__ __launch_bounds__(512, 2) void k_rsweep(
    const float* __restrict__ x, const float* __restrict__ W,
    const float* __restrict__ sA, float scaleA,
    const float* __restrict__ sB,  // may be null
    const float* __restrict__ bias,
    float* __restrict__ part)
{
  __shared__ float4 bufA[64 * 65];   // 66560 B
  __shared__ float4 bufB[64 * 65];   // 66560 B
  const int t = threadIdx.x;
  const int o = t & 63;
  const int wv = t >> 6;
  const int i0 = blockIdx.x * 8;

  // vv = squash(sA*scaleA + bias) [+ squash(sB + bias)], per (bb, d)
  float vvA[2][16], vvB[2][16];
#pragma unroll
  for (int bb = 0; bb < 2; ++bb) {
    const int b = wv * 2 + bb;
    const float* sa = sA + b * OD_ + o * 32;
    const float* sb = sB ? sB + b * OD_ + o * 32 : nullptr;
    const float* bp = bias + o * 32;
#pragma unroll
    for (int d = 0; d < 16; ++d) {
      float bs0 = bp[d], bs1 = bp[d + 16];
      float va = squashf(sa[d] * scaleA + bs0);
      float vb = squashf(sa[d + 16] * scaleA + bs1);
      if (sb) { va += squashf(sb[d] + bs0); vb += squashf(sb[d + 16] + bs1); }
      vvA[bb][d] = va; vvB[bb][d] = vb;
    }
  }

  float accA[2][16], accB[2][16];
#pragma unroll
  for (int bb = 0; bb < 2; ++bb)
#pragma unroll
    for (int d = 0; d < 16; ++d) { accA[bb][d] = 0.f; accB[bb][d] = 0.f; }

  // prologue: A(0) staged+drained; B(0) in flight
  const float* Wrow0 = W + (size_t)i0 * (OD_ * 16);
  STAGE_HALF(Wrow0, 0, bufA);
  __syncthreads();
  STAGE_HALF(Wrow0, 1, bufB);

  for (int ii = 0; ii < 8; ++ii) {
    const int i = i0 + ii;
    const float* Wnext = W + (size_t)(i + 1) * (OD_ * 16);

    // x -> SGPRs (uniform per wave-iteration)
    float xsv[2][16];
#pragma unroll
    for (int bb = 0; bb < 2; ++bb) {
      const float4* xp = (const float4*)(x + ((size_t)((wv * 2 + bb) * I_) + i) * 16);
#pragma unroll
      for (int q = 0; q < 4; ++q) {
        float4 xq = xp[q];
        xsv[bb][q * 4 + 0] = rfl(xq.x); xsv[bb][q * 4 + 1] = rfl(xq.y);
        xsv[bb][q * 4 + 2] = rfl(xq.z); xsv[bb][q * 4 + 3] = rfl(xq.w);
      }
    }

    float lg[2] = {0.f, 0.f};
    float uA[2][16], uB[2][16];

    // ---- compute half A (d = 0..15) from bufA ----
#pragma unroll
    for (int d = 0; d < 16; ++d) {
      const float4* wp = bufA + o * 65 + d * 4;
      float4 w0 = wp[0], w1 = wp[1], w2 = wp[2], w3 = wp[3];
#pragma unroll
      for (int bb = 0; bb < 2; ++bb) {
        float uu = xsv[bb][0] * w0.x;
        uu = fmaf(xsv[bb][1], w0.y, uu); uu = fmaf(xsv[bb][2], w0.z, uu);
        uu = fmaf(xsv[bb][3], w0.w, uu); uu = fmaf(xsv[bb][4], w1.x, uu);
        uu = fmaf(xsv[bb][5], w1.y, uu); uu = fmaf(xsv[bb][6], w1.z, uu);
        uu = fmaf(xsv[bb][7], w1.w, uu); uu = fmaf(xsv[bb][8], w2.x, uu);
        uu = fmaf(xsv[bb][9], w2.y, uu); uu = fmaf(xsv[bb][10], w2.z, uu);
        uu = fmaf(xsv[bb][11], w2.w, uu); uu = fmaf(xsv[bb][12], w3.x, uu);
        uu = fmaf(xsv[bb][13], w3.y, uu); uu = fmaf(xsv[bb][14], w3.z, uu);
        uu = fmaf(xsv[bb][15], w3.w, uu);
        uA[bb][d] = uu;
        lg[bb] = fmaf(uu, vvA[bb][d], lg[bb]);
      }
    }
    __syncthreads();                 // bufB(ii) complete; all done with bufA
    if (ii < 7) STAGE_HALF(Wnext, 0, bufA);

    // ---- compute half B (d = 16..31) from bufB ----
#pragma unroll
    for (int d = 0; d < 16; ++d) {
      const float4* wp = bufB + o * 65 + d * 4;
      float4 w0 = wp[0], w1 = wp[1], w2 = wp[2], w3 = wp[3];
#pragma unroll
      for (int bb = 0; bb < 2; ++bb) {
        float uu = xsv[bb][0] * w0.x;
        uu = fmaf(xsv[bb][1], w0.y, uu); uu = fmaf(xsv[bb][2], w0.z, uu);
        uu = fmaf(xsv[bb][3], w0.w, uu); uu = fmaf(xsv[bb][4], w1.x, uu);
        uu = fmaf(xsv[bb][5], w1.y, uu); uu = fmaf(xsv[bb][6], w1.z, uu);
        uu = fmaf(xsv[bb][7], w1.w, uu); uu = fmaf(xsv[bb][8], w2.x, uu);
        uu = fmaf(xsv[bb][9], w2.y, uu); uu = fmaf(xsv[bb][10], w2.z, uu);
        uu = fmaf(xsv[bb][11], w2.w, uu); uu = fmaf(xsv[bb][12], w3.x, uu);
        uu = fmaf(xsv[bb][13], w3.y, uu); uu = fmaf(xsv[bb][14], w3.z, uu);
        uu = fmaf(xsv[bb][15], w3.w, uu);
        uB[bb][d] = uu;
        lg[bb] = fmaf(uu, vvB[bb][d], lg[bb]);
      }
    }

    // ---- exact softmax over o (64 lanes) per bb, then accumulate ----
#pragma unroll
    for (int bb = 0; bb < 2; ++bb) {
      float m = lg[bb];
#pragma unroll
      for (int off = 32; off > 0; off >>= 1) m = fmaxf(m, __shfl_xor(m, off, 64));
      float ex = __expf(lg[bb] - m);
      float sm = ex;
#pragma unroll
      for (int off = 32; off > 0; off >>= 1) sm += __shfl_xor(sm, off, 64);
      float c = ex * __builtin_amdgcn_rcpf(sm);
#pragma unroll
      for (int d = 0; d < 16; ++d) {
        accA[bb][d] = fmaf(c, uA[bb][d], accA[bb][d]);
        accB[bb][d] = fmaf(c, uB[bb][d], accB[bb][d]);
      }
    }
    __syncthreads();                 // bufA(ii+1) complete; all done with bufB
    if (ii < 7) STAGE_HALF(Wnext, 1, bufB);
  }

  // ---- write per-(wave,b) partial: part[(b*256 + blk)][o*32 + d] ----
#pragma unroll
  for (int bb = 0; bb < 2; ++bb) {
    const int b = wv * 2 + bb;
    float4* dst = (float4*)(part + ((size_t)(b * 256 + blockIdx.x)) * OD_ + o * 32);
#pragma unroll
    for (int q = 0; q < 4; ++q) {
      float4 v0, v1;
      v0.x = accA[bb][q * 4 + 0]; v0.y = accA[bb][q * 4 + 1];
      v0.z = accA[bb][q * 4 + 2]; v0.w = accA[bb][q * 4 + 3];
      v1.x = accB[bb][q * 4 + 0]; v1.y = accB[bb][q * 4 + 1];
      v1.z = accB[bb][q * 4 + 2]; v1.w = accB[bb][q * 4 + 3];
      dst[q] = v0; dst[q + 4] = v1;
    }
  }
}

// ---------------------------------------------------------------------------
// K4: s1[b,od] = sum_g part[(b*256+g)][od].  grid=128.
// ---------------------------------------------------------------------------
__global__ __launch_bounds__(256) void k_s1red(
    const float* __restrict__ part, float* __restrict__ s1)
{
  const int b = blockIdx.x >> 3;
  const int od = (blockIdx.x & 7) * 256 + threadIdx.x;
  float a = 0.f;
  const float* p = part + (size_t)b * 256 * OD_ + od;
#pragma unroll 8
  for (int g = 0; g < 256; ++g) a += p[(size_t)g * OD_];
  s1[b * OD_ + od] = a;
}

// ---------------------------------------------------------------------------
// K5: out[b,od] = squash(sum_g part2 + bias).  grid=128.
// ---------------------------------------------------------------------------
__global__ __launch_bounds__(256) void k_outred(
    const float* __restrict__ part, const float* __restrict__ bias,
    float* __restrict__ out)
{
  const int b = blockIdx.x >> 3;
  const int od = (blockIdx.x & 7) * 256 + threadIdx.x;
  float a = 0.f;
  const float* p = part + (size_t)b * 256 * OD_ + od;
#pragma unroll 8
  for (int g = 0; g < 256; ++g) a += p[(size_t)g * OD_];
  out[b * OD_ + od] = squashf(a + bias[od]);
}

extern "C" void kernel_launch(void* const* d_in, const int* in_sizes, int n_in,
                              void* d_out, int out_size, void* d_ws, size_t ws_size,
                              hipStream_t stream) {
  const float* x = (const float*)d_in[0];
  const float* W = (const float*)d_in[1];
  const float* bias = (const float*)d_in[2];
  float* out = (float*)d_out;

  char* ws = (char*)d_ws;
  float* part0 = (float*)ws;                          // 32 MB s0 partials
  float* part1 = (float*)(ws + 33554432ull);          // 32 MB route partials
  float* part2 = part0;                               // reuse: part0 dead after K2
  float* s0    = (float*)(ws + 67108864ull);          // 128 KB
  float* s1    = s0 + 32768;                          // 128 KB

  k_s0sweep<<<dim3(2048), dim3(256), 0, stream>>>(x, W, part0);
  k_s0red  <<<dim3(128),  dim3(256), 0, stream>>>(part0, s0);
  // pass1: v0 = squash(s0/64 + bias)
  k_rsweep <<<dim3(256),  dim3(512), 0, stream>>>(x, W, s0, 1.0f / 64.0f, nullptr, bias, part1);
  k_s1red  <<<dim3(128),  dim3(256), 0, stream>>>(part1, s1);
  // pass2: vv = squash(s0/64+bias) + squash(s1+bias)
  k_rsweep <<<dim3(256),  dim3(512), 0, stream>>>(x, W, s0, 1.0f / 64.0f, s1, bias, part2);
  k_outred <<<dim3(128),  dim3(256), 0, stream>>>(part2, bias, out);
}

// Round 12
// 614.722 us; speedup vs baseline: 1.4770x; 1.0123x over previous
//
#include <hip/hip_runtime.h>

// RoutingCapsule: x(16,2048,16) fp32, W(1,2048,64,32,16) fp32, bias(64,32) fp32
// -> v(16,64,32) fp32.   Routing collapses (b_logits additive from 0):
//   s0 = (1/64) sum_i u ; v0 = squash(s0+bias)
//   pass1: c1 = softmax_o(u.v0)      ; s1 = sum_i c1*u
//   pass2: c2 = softmax_o(u.(v0+v1)) ; out = squash(sum_i c2*u + bias)
//
// R18: R17 died on "container failed twice" — 3rd occurrence of the
// source-independent infra mode (R8->R9 and R13->R14 identical resubmits
// both ran fine). R17 source re-audited for NEW-mechanic hazards:
// prologue stage(0) drained by the compiler's vmcnt(0)-before-s_barrier;
// counted vmcnt(4) is per-wave and quarters are wave-private (no cross-wave
// LDS dep); sched_barrier(0) after each asm waitcnt (rule #18); all bounds
// unchanged from passing R15/R16. No defect found -> resubmit unchanged.
//
// R17 theory (stands): R15==R16 (~116us s0sweep) because both burst 16KB
// then drain per ii => HBM duty ~40%; R16 also had a 32-way bank conflict
// on consume (wbuf[t*4] = byte t*64). Fix: (a) source-swizzled wave-private
// staging (wave stages exactly what it consumes -> no loop barriers);
// (b) consume at 16B lane stride (slots t, t+256, t+512, t+768) = 0
// conflicts; (c) counted s_waitcnt vmcnt(4), never 0 in-loop -> 16
// staggered waves/CU keep 64-128KB in flight. VGPR ~70, LDS 40960B.
// rsweep/reducers/launcher: byte-identical to R15/R16.
#define B_ 16
#define I_ 2048
#define OD_ 2048
#define EPSQ 1e-9f

typedef float v4f __attribute__((ext_vector_type(4)));

__device__ __forceinline__ float squashf(float s) {
  float sq = s * s;
  return sq / (1.0f + sq) * s * rsqrtf(sq + EPSQ);
}

__device__ __forceinline__ float dot4(v4f a, v4f b) {
  return a.x * b.x + a.y * b.y + a.z * b.z + a.w * b.w;
}

__device__ __forceinline__ void gload16(const void* g, void* l) {
  __builtin_amdgcn_global_load_lds(
      (__attribute__((address_space(1))) const unsigned int*)g,
      (__attribute__((address_space(3))) unsigned int*)l, 16, 0, 0);
}

__device__ __forceinline__ float rfl(float v) {
  return __uint_as_float(__builtin_amdgcn_readfirstlane(__float_as_uint(v)));
}

// ---- staging macro for k_rsweep (locals t/wv in scope at expansion).
// Wave stages 8 o-slices (1 KB each) of a 64KB W d-half into a
// 65-float4-stride padded LDS buffer: linear per-instruction dest (required
// by global_load_lds), pad falls between instructions; stride 65 == 1 mod 8
// -> conflict-free ds_read_b128 on the consume side. ----
#define STAGE_HALF(row, half, buf)                                         \
  {                                                                        \
    _Pragma("unroll")                                                      \
    for (int k = 0; k < 8; ++k) {                                          \
      const int oo = wv + k * 8;                                           \
      const float* g = (row) + oo * 512 + (half) * 256 + (t & 63) * 4;     \
      gload16(g, (void*)((char*)(buf) + (size_t)(oo * 65) * 16));          \
    }                                                                      \
  }

// ---------------------------------------------------------------------------
// K1: s0 partials only (no u materialization).
// grid=2048: bx&7 = od-eighth e, bx>>3 = i-chunk ic (8 i each). Thread owns
// od = e*256+t.  Wave-private W staging: wave wv stages its own 4KB quarter
// per ii (4 gload16, pre-swizzled source), double-buffered, counted vmcnt(4)
// between issue and consume — NO barriers after the x-stage. Consume is 4x
// ds_read_b128 at 16B lane stride (conflict-free).
// part0[ic][b][od] : 256*16*2048 fp32 = 32 MB.
// ---------------------------------------------------------------------------
__global__ __launch_bounds__(256, 4) void k_s0sweep(
    const float* __restrict__ x, const float* __restrict__ W,
    float* __restrict__ part0)
{
  __shared__ v4f  wbuf[2][1024];     // 2 x 16 KB, wave-private quarters
  __shared__ float xs[8 * 16 * 16];  // [ii][b][p] 8 KB
  const int t = threadIdx.x;
  const int wv = t >> 6;
  const int ln = t & 63;
  const int e = blockIdx.x & 7;
  const int ic = blockIdx.x >> 3;
  const int i0 = ic * 8;
  const int od = e * 256 + t;

  // stage x[b, i0..i0+7, :] -> xs[ii][b][p]  (R15/R16-exact)
  {
    const int b = t >> 4, j = t & 15;
    const float4* src = (const float4*)(x + (size_t)(b * I_ + i0) * 16);
    float4 a0 = src[j * 2], a1 = src[j * 2 + 1];
    const int ii = j >> 1, pq = (j & 1) * 2;
    float4* dst = (float4*)xs + ii * 64 + b * 4;
    dst[pq] = a0; dst[pq + 1] = a1;
  }

  // Wave-private stage of row i's 16KB slice, quarter owned by wave wv.
  // slot s = r*256 + wv*64 + ln  holds  slice float4 g4 = 256*wv + 4*ln + r
  // (bijective). Thread t's own data (g4 = 4t+r) lands at slots t + r*256.
  // dest wave-uniform (wv,r) + lane*16 by HW; src per-lane (pre-swizzle).
#define S0_STAGE(iidx, p)                                                  \
  {                                                                        \
    const float* sl_ = W + ((size_t)(i0 + (iidx)) * OD_ + e * 256) * 16;   \
    _Pragma("unroll")                                                      \
    for (int r = 0; r < 4; ++r) {                                          \
      gload16(sl_ + 1024 * wv + 16 * ln + 4 * r,                           \
              (void*)((char*)(&wbuf[p][0]) + (r * 256 + wv * 64) * 16));   \
    }                                                                      \
  }

  float s0acc[B_];
#pragma unroll
  for (int b = 0; b < B_; ++b) s0acc[b] = 0.f;

  S0_STAGE(0, 0);       // in flight during x barrier (drained by it: vmcnt(0))
  __syncthreads();      // x visible to all waves; stage(0) complete

  for (int ii = 0; ii < 8; ++ii) {
    if (ii < 7) {
      S0_STAGE(ii + 1, (ii + 1) & 1);                 // issue next quarter
      asm volatile("s_waitcnt vmcnt(4)" ::: "memory"); // wait only ii's 4 loads
      __builtin_amdgcn_sched_barrier(0);
    } else {
      asm volatile("s_waitcnt vmcnt(0)" ::: "memory");
      __builtin_amdgcn_sched_barrier(0);
    }

    const v4f* bp = &wbuf[ii & 1][t];   // lane stride 16B: conflict-free
    v4f w0 = bp[0], w1 = bp[256], w2 = bp[512], w3 = bp[768];
    const v4f* xv = (const v4f*)xs + ii * 64;
#pragma unroll
    for (int b = 0; b < B_; ++b) {
      v4f x0 = xv[b * 4 + 0], x1 = xv[b * 4 + 1];
      v4f x2 = xv[b * 4 + 2], x3 = xv[b * 4 + 3];
      s0acc[b] += dot4(x0, w0) + dot4(x1, w1) +
                  dot4(x2, w2) + dot4(x3, w3);
    }
    // no barrier: wbuf quarters are wave-private; parity is per-wave local
  }
#undef S0_STAGE

#pragma unroll
  for (int b = 0; b < B_; ++b)
    part0[((size_t)ic * B_ + b) * OD_ + od] = s0acc[b];
}

// ---------------------------------------------------------------------------
// K2: s0_raw[b,od] = sum_ic part0[ic][b][od].  grid=128: b=bx>>3, od block.
// ---------------------------------------------------------------------------
__global__ __launch_bounds__(256) void k_s0red(
    const float* __restrict__ part0, float* __restrict__ s0)
{
  const int b = blockIdx.x >> 3;
  const int od = (blockIdx.x & 7) * 256 + threadIdx.x;
  float a = 0.f;
  const float* p = part0 + (size_t)b * OD_ + od;
#pragma unroll 8
  for (int ic = 0; ic < 256; ++ic) a += p[(size_t)ic * B_ * OD_];
  s0[b * OD_ + od] = a;
}

// ---------------------------------------------------------------------------
// K3: fused routing sweep — recomputes u from W/x, W streamed exactly once.
// [R15/R16-exact] 256 blocks x 512 thr (8 waves, 1 block/CU, LDS 133KB).
// Block owns 8 i. Wave wv owns b = 2wv, 2wv+1; lane = o. Per i: W row staged
// in two 64KB d-halves, double-buffered; u kept in regs; exact softmax per
// (b,i); one 8KB partial write per (wave,b). part[(b*256 + blk)][od] : 32 MB.
// ---------------------------------------------------------------------------
__global__ __launch_bounds__(512, 2) void k_rsweep(
    const float* __restrict__ x, const float* __restrict__ W,
    const float* __restrict__ sA, float scaleA,
    const float* __restrict__ sB,  // may be null
    const float* __restrict__ bias,
    float* __restrict__ part)
{
  __shared__ float4 bufA[64 * 65];   // 66560 B
  __shared__ float4 bufB[64 * 65];   // 66560 B
  const int t = threadIdx.x;
  const int o = t & 63;
  const int wv = t >> 6;
  const int i0 = blockIdx.x * 8;

  // vv = squash(sA*scaleA + bias) [+ squash(sB + bias)], per (bb, d)
  float vvA[2][16], vvB[2][16];
#pragma unroll
  for (int bb = 0; bb < 2; ++bb) {
    const int b = wv * 2 + bb;
    const float* sa = sA + b * OD_ + o * 32;
    const float* sb = sB ? sB + b * OD_ + o * 32 : nullptr;
    const float* bp = bias + o * 32;
#pragma unroll
    for (int d = 0; d < 16; ++d) {
      float bs0 = bp[d], bs1 = bp[d + 16];
      float va = squashf(sa[d] * scaleA + bs0);
      float vb = squashf(sa[d + 16] * scaleA + bs1);
      if (sb) { va += squashf(sb[d] + bs0); vb += squashf(sb[d + 16] + bs1); }
      vvA[bb][d] = va; vvB[bb][d] = vb;
    }
  }

  float accA[2][16], accB[2][16];
#pragma unroll
  for (int bb = 0; bb < 2; ++bb)
#pragma unroll
    for (int d = 0; d < 16; ++d) { accA[bb][d] = 0.f; accB[bb][d] = 0.f; }

  // prologue: A(0) staged+drained; B(0) in flight
  const float* Wrow0 = W + (size_t)i0 * (OD_ * 16);
  STAGE_HALF(Wrow0, 0, bufA);
  __syncthreads();
  STAGE_HALF(Wrow0, 1, bufB);

  for (int ii = 0; ii < 8; ++ii) {
    const int i = i0 + ii;
    const float* Wnext = W + (size_t)(i + 1) * (OD_ * 16);

    // x -> SGPRs (uniform per wave-iteration)
    float xsv[2][16];
#pragma unroll
    for (int bb = 0; bb < 2; ++bb) {
      const float4* xp = (const float4*)(x + ((size_t)((wv * 2 + bb) * I_) + i) * 16);
#pragma unroll
      for (int q = 0; q < 4; ++q) {
        float4 xq = xp[q];
        xsv[bb][q * 4 + 0] = rfl(xq.x); xsv[bb][q * 4 + 1] = rfl(xq.y);
        xsv[bb][q * 4 + 2] = rfl(xq.z); xsv[bb][q * 4 + 3] = rfl(xq.w);
      }
    }

    float lg[2] = {0.f, 0.f};
    float uA[2][16], uB[2][16];

    // ---- compute half A (d = 0..15) from bufA ----
#pragma unroll
    for (int d = 0; d < 16; ++d) {
      const float4* wp = bufA + o * 65 + d * 4;
      float4 w0 = wp[0], w1 = wp[1], w2 = wp[2], w3 = wp[3];
#pragma unroll
      for (int bb = 0; bb < 2; ++bb) {
        float uu = xsv[bb][0] * w0.x;
        uu = fmaf(xsv[bb][1], w0.y, uu); uu = fmaf(xsv[bb][2], w0.z, uu);
        uu = fmaf(xsv[bb][3], w0.w, uu); uu = fmaf(xsv[bb][4], w1.x, uu);
        uu = fmaf(xsv[bb][5], w1.y, uu); uu = fmaf(xsv[bb][6], w1.z, uu);
        uu = fmaf(xsv[bb][7], w1.w, uu); uu = fmaf(xsv[bb][8], w2.x, uu);
        uu = fmaf(xsv[bb][9], w2.y, uu); uu = fmaf(xsv[bb][10], w2.z, uu);
        uu = fmaf(xsv[bb][11], w2.w, uu); uu = fmaf(xsv[bb][12], w3.x, uu);
        uu = fmaf(xsv[bb][13], w3.y, uu); uu = fmaf(xsv[bb][14], w3.z, uu);
        uu = fmaf(xsv[bb][15], w3.w, uu);
        uA[bb][d] = uu;
        lg[bb] = fmaf(uu, vvA[bb][d], lg[bb]);
      }
    }
    __syncthreads();                 // bufB(ii) complete; all done with bufA
    if (ii < 7) STAGE_HALF(Wnext, 0, bufA);

    // ---- compute half B (d = 16..31) from bufB ----
#pragma unroll
    for (int d = 0; d < 16; ++d) {
      const float4* wp = bufB + o * 65 + d * 4;
      float4 w0 = wp[0], w1 = wp[1], w2 = wp[2], w3 = wp[3];
#pragma unroll
      for (int bb = 0; bb < 2; ++bb) {
        float uu = xsv[bb][0] * w0.x;
        uu = fmaf(xsv[bb][1], w0.y, uu); uu = fmaf(xsv[bb][2], w0.z, uu);
        uu = fmaf(xsv[bb][3], w0.w, uu); uu = fmaf(xsv[bb][4], w1.x, uu);
        uu = fmaf(xsv[bb][5], w1.y, uu); uu = fmaf(xsv[bb][6], w1.z, uu);
        uu = fmaf(xsv[bb][7], w1.w, uu); uu = fmaf(xsv[bb][8], w2.x, uu);
        uu = fmaf(xsv[bb][9], w2.y, uu); uu = fmaf(xsv[bb][10], w2.z, uu);
        uu = fmaf(xsv[bb][11], w2.w, uu); uu = fmaf(xsv[bb][12], w3.x, uu);
        uu = fmaf(xsv[bb][13], w3.y, uu); uu = fmaf(xsv[bb][14], w3.z, uu);
        uu = fmaf(xsv[bb][15], w3.w, uu);
        uB[bb][d] = uu;
        lg[bb] = fmaf(uu, vvB[bb][d], lg[bb]);
      }
    }

    // ---- exact softmax over o (64 lanes) per bb, then accumulate ----
#pragma unroll
    for (int bb = 0; bb < 2; ++bb) {
      float m = lg[bb];
#pragma unroll
      for (int off = 32; off > 0; off >>= 1) m = fmaxf(m, __shfl_xor(m, off, 64));
      float ex = __expf(lg[bb] - m);
      float sm = ex;
#pragma unroll
      for (int off = 32; off > 0; off >>= 1) sm += __shfl_xor(sm, off, 64);
      float c = ex * __builtin_amdgcn_rcpf(sm);
#pragma unroll
      for (int d = 0; d < 16; ++d) {
        accA[bb][d] = fmaf(c, uA[bb][d], accA[bb][d]);
        accB[bb][d] = fmaf(c, uB[bb][d], accB[bb][d]);
      }
    }
    __syncthreads();                 // bufA(ii+1) complete; all done with bufB
    if (ii < 7) STAGE_HALF(Wnext, 1, bufB);
  }

  // ---- write per-(wave,b) partial: part[(b*256 + blk)][o*32 + d] ----
#pragma unroll
  for (int bb = 0; bb < 2; ++bb) {
    const int b = wv * 2 + bb;
    float4* dst = (float4*)(part + ((size_t)(b * 256 + blockIdx.x)) * OD_ + o * 32);
#pragma unroll
    for (int q = 0; q < 4; ++q) {
      float4 v0, v1;
      v0.x = accA[bb][q * 4 + 0]; v0.y = accA[bb][q * 4 + 1];
      v0.z = accA[bb][q * 4 + 2]; v0.w = accA[bb][q * 4 + 3];
      v1.x = accB[bb][q * 4 + 0]; v1.y = accB[bb][q * 4 + 1];
      v1.z = accB[bb][q * 4 + 2]; v1.w = accB[bb][q * 4 + 3];
      dst[q] = v0; dst[q + 4] = v1;
    }
  }
}

// ---------------------------------------------------------------------------
// K4: s1[b,od] = sum_g part[(b*256+g)][od].  grid=128.
// ---------------------------------------------------------------------------
__global__ __launch_bounds__(256) void k_s1red(
    const float* __restrict__ part, float* __restrict__ s1)
{
  const int b = blockIdx.x >> 3;
  const int od = (blockIdx.x & 7) * 256 + threadIdx.x;
  float a = 0.f;
  const float* p = part + (size_t)b * 256 * OD_ + od;
#pragma unroll 8
  for (int g = 0; g < 256; ++g) a += p[(size_t)g * OD_];
  s1[b * OD_ + od] = a;
}

// ---------------------------------------------------------------------------
// K5: out[b,od] = squash(sum_g part2 + bias).  grid=128.
// ---------------------------------------------------------------------------
__global__ __launch_bounds__(256) void k_outred(
    const float* __restrict__ part, const float* __restrict__ bias,
    float* __restrict__ out)
{
  const int b = blockIdx.x >> 3;
  const int od = (blockIdx.x & 7) * 256 + threadIdx.x;
  float a = 0.f;
  const float* p = part + (size_t)b * 256 * OD_ + od;
#pragma unroll 8
  for (int g = 0; g < 256; ++g) a += p[(size_t)g * OD_];
  out[b * OD_ + od] = squashf(a + bias[od]);
}

extern "C" void kernel_launch(void* const* d_in, const int* in_sizes, int n_in,
                              void* d_out, int out_size, void* d_ws, size_t ws_size,
                              hipStream_t stream) {
  const float* x = (const float*)d_in[0];
  const float* W = (const float*)d_in[1];
  const float* bias = (const float*)d_in[2];
  float* out = (float*)d_out;

  char* ws = (char*)d_ws;
  float* part0 = (float*)ws;                          // 32 MB s0 partials
  float* part1 = (float*)(ws + 33554432ull);          // 32 MB route partials
  float* part2 = part0;                               // reuse: part0 dead after K2
  float* s0    = (float*)(ws + 67108864ull);          // 128 KB
  float* s1    = s0 + 32768;                          // 128 KB

  k_s0sweep<<<dim3(2048), dim3(256), 0, stream>>>(x, W, part0);
  k_s0red  <<<dim3(128),  dim3(256), 0, stream>>>(part0, s0);
  // pass1: v0 = squash(s0/64 + bias)
  k_rsweep <<<dim3(256),  dim3(512), 0, stream>>>(x, W, s0, 1.0f / 64.0f, nullptr, bias, part1);
  k_s1red  <<<dim3(128),  dim3(256), 0, stream>>>(part1, s1);
  // pass2: vv = squash(s0/64+bias) + squash(s1+bias)
  k_rsweep <<<dim3(256),  dim3(512), 0, stream>>>(x, W, s0, 1.0f / 64.0f, s1, bias, part2);
  k_outred <<<dim3(128),  dim3(256), 0, stream>>>(part2, bias, out);
}